// Round 16
// baseline (2090.478 us; speedup 1.0000x reference)
//
#include <hip/hip_runtime.h>
#include <math.h>

#define BATCH 256
#define TT    784
#define HH    512
#define NCLS  10

#define NB 64          // batch groups
#define NJ 4           // blocks per group; block owns 128 cols
#define MB 4           // batch rows per group
#define HJ 128         // output cols per block
#define NT 512         // threads per block (8 waves, 2/SIMD)

typedef unsigned long long ull;
typedef unsigned int uint32;

#define AL(p)    __hip_atomic_load((p), __ATOMIC_RELAXED, __HIP_MEMORY_SCOPE_AGENT)
#define AS(p, v) __hip_atomic_store((p), (v), __ATOMIC_RELAXED, __HIP_MEMORY_SCOPE_AGENT)

// R0-R15 LESSONS (journal) — backbone = R12 (2023-2027 us, reproduced):
//  * Self-validating (value,tag) 8B publishes (R12, -26%): no vmcnt drain,
//    no flag; consumer polls its OWN words, tag-match => value in-register.
//  * All-thread scalar reduce + conflict-free scalar pbuf (R8, -12%).
//  * Own-slice stays on-CU via LDS + barrier C (R7/R13: L2 route = +loss).
//  * Poll pre-issue before barrier C races the publish -> stale (R14 loss).
//  * 1 block/CU, 2 waves/SIMD optimal (R6/R9 losses). Unified VGPR+AGPR
//    file keeps the 128 weight floats resident (R8: VGPR=92, no scratch).
//  * Cross-CU reads MUST bypass L1 (R10 absmax=8: stale L1 via plain DMA).
//  * VALUBusy on gfx950 ~2x inflated (gfx94x SIMD-16 formula): 80 ~= 36%.
//  * THIS ROUND: the exchange ran entirely through L3 (agent-scope = sc0
//    sc1). Group members (blk=bb+64g, 64%8==0) share an XCD under the %8
//    dispatch heuristic -> the shared per-XCD L2 can serve the poll at
//    ~200 cyc instead of ~500. Fast path: inline-asm sc0-ONLY loads (bypass
//    L1, hit XCD L2 — producer's sc1 store either updates or invalidates
//    that line, both give fresh data same-XCD). Fallback in the same loop:
//    the proven agent-scope loads — correctness NEVER depends on the XCD
//    mapping (Guideline 16); worst case is bounded extra poll work.
//
// d_ws layout:
//   [8192, 8192+2MB) : hbufU ull[2][BATCH][HH] — (tag<<32)|float_bits,
//                      agent-relaxed. Tags zeroed by hipMemsetAsync each
//                      launch (resets between bench iterations).

// Opaque register pin: weights become outputs of a volatile asm — cannot be
// rematerialized or sunk into the loop.
#define PIN(V) asm volatile("" : "+v"((V).x), "+v"((V).y), "+v"((V).z), "+v"((V).w))

__global__ __launch_bounds__(NT)
__attribute__((amdgpu_waves_per_eu(2, 2)))
void rnn_main_kernel(
    const float* __restrict__ inputs, const int* __restrict__ order,
    const float* __restrict__ W_ih, const float* __restrict__ b_ih,
    const float* __restrict__ W_hh, const float* __restrict__ b_hh,
    ull* __restrict__ hbufU)
{
    __shared__ float hp[MB * HH];            // 8 KB : h tile (canonical col layout)
    __shared__ float pbuf[16 * MB * HJ];     // 32 KB: partials, SCALAR [kk][row][col]
    __shared__ float xall[TT * MB];          // 12.25 KB: inputs[b][order[t]]
    __shared__ float wih_s[HJ];
    __shared__ float bias_s[HJ];

    const int tid   = threadIdx.x;
    const int blk   = blockIdx.x;
    const int bb    = blk & (NB - 1);        // group; members blk=bb+64g -> same XCD under %8
    const int jjg   = blk >> 6;              // producer id 0..3: cols [jjg*128, +128)
    const int jbase = jjg * HJ;
    const int bbase = bb * MB;
    const int j   = tid & 31;                // base col lane: cols {j, j+32, j+64, j+96}
    const int kg  = tid >> 5;                // k-chunk 0..15 (32 k each)
    const int w   = tid >> 6;                // wave: k-window [64w,+64), producer g=w>>1
    const int g   = w >> 1;
    const int l   = tid & 63;

    // ---- W_hh slice in NAMED registers: 4 cols x 32 k = 32 float4
    //      (live in the unified VGPR/AGPR file; VALU reads them directly)
    const float4* wpa = (const float4*)(W_hh + (size_t)(jbase + j +  0) * HH + kg * 32);
    const float4* wpb = (const float4*)(W_hh + (size_t)(jbase + j + 32) * HH + kg * 32);
    const float4* wpc = (const float4*)(W_hh + (size_t)(jbase + j + 64) * HH + kg * 32);
    const float4* wpd = (const float4*)(W_hh + (size_t)(jbase + j + 96) * HH + kg * 32);
    float4 wa0 = wpa[0], wa1 = wpa[1], wa2 = wpa[2], wa3 = wpa[3];
    float4 wa4 = wpa[4], wa5 = wpa[5], wa6 = wpa[6], wa7 = wpa[7];
    float4 wb0 = wpb[0], wb1 = wpb[1], wb2 = wpb[2], wb3 = wpb[3];
    float4 wb4 = wpb[4], wb5 = wpb[5], wb6 = wpb[6], wb7 = wpb[7];
    float4 wc0 = wpc[0], wc1 = wpc[1], wc2 = wpc[2], wc3 = wpc[3];
    float4 wc4 = wpc[4], wc5 = wpc[5], wc6 = wpc[6], wc7 = wpc[7];
    float4 wd0 = wpd[0], wd1 = wpd[1], wd2 = wpd[2], wd3 = wpd[3];
    float4 wd4 = wpd[4], wd5 = wpd[5], wd6 = wpd[6], wd7 = wpd[7];

    PIN(wa0); PIN(wa1); PIN(wa2); PIN(wa3);
    PIN(wa4); PIN(wa5); PIN(wa6); PIN(wa7);
    PIN(wb0); PIN(wb1); PIN(wb2); PIN(wb3);
    PIN(wb4); PIN(wb5); PIN(wb6); PIN(wb7);
    PIN(wc0); PIN(wc1); PIN(wc2); PIN(wc3);
    PIN(wc4); PIN(wc5); PIN(wc6); PIN(wc7);
    PIN(wd0); PIN(wd1); PIN(wd2); PIN(wd3);
    PIN(wd4); PIN(wd5); PIN(wd6); PIN(wd7);

    if (tid < HJ) {
        wih_s[tid]  = W_ih[jbase + tid];
        bias_s[tid] = b_ih[jbase + tid] + b_hh[jbase + tid];
    }
    for (int idx = tid; idx < TT * MB; idx += NT) {
        const int t = idx >> 2;
        const int b = idx & (MB - 1);
        xall[idx] = inputs[(size_t)(bbase + b) * TT + order[t]];
    }
    ((float4*)hp)[tid] = make_float4(0.f, 0.f, 0.f, 0.f);   // h_0 = 0 (8 KB)
    __syncthreads();

    const float4* hp4 = (const float4*)hp;

    for (int t = 0; t < TT; ++t) {
        const int p = t & 1;

        // ---- per-wave gate+stage fused: each lane polls ITS OWN 4 pair-words
        //      (one per batch row at col w*64+l). Fast path = sc0-only loads
        //      (XCD-local L2, ~200 cyc); fallback = agent-scope loads (L3,
        //      always correct). Tag match => value already in-register.
        if (t > 0 && g != jjg) {
            const uint32 tg = (uint32)t;
            const ull* s0 = hbufU + (size_t)p * BATCH * HH
                            + (size_t)bbase * HH + w * 64 + l;
            const ull* s1 = s0 + HH;
            const ull* s2 = s0 + 2 * HH;
            const ull* s3 = s0 + 3 * HH;
            ull u0, u1, u2, u3;
            for (;;) {
                // FAST: sc0 only — bypass L1, served by this XCD's shared L2.
                asm volatile(
                    "global_load_dwordx2 %0, %4, off sc0\n\t"
                    "global_load_dwordx2 %1, %5, off sc0\n\t"
                    "global_load_dwordx2 %2, %6, off sc0\n\t"
                    "global_load_dwordx2 %3, %7, off sc0\n\t"
                    "s_waitcnt vmcnt(0)"
                    : "=&v"(u0), "=&v"(u1), "=&v"(u2), "=&v"(u3)
                    : "v"(s0), "v"(s1), "v"(s2), "v"(s3)
                    : "memory");
                int ok = ((uint32)(u0 >> 32) >= tg) & ((uint32)(u1 >> 32) >= tg)
                       & ((uint32)(u2 >> 32) >= tg) & ((uint32)(u3 >> 32) >= tg);
                if (__all(ok)) break;
                // CORRECT: agent scope (sc0 sc1, reads L3) — guarantees
                // progress even if the local L2 line is valid-stale or the
                // producer landed on another XCD. Never depends on mapping.
                u0 = AL(s0); u1 = AL(s1); u2 = AL(s2); u3 = AL(s3);
                ok = ((uint32)(u0 >> 32) >= tg) & ((uint32)(u1 >> 32) >= tg)
                   & ((uint32)(u2 >> 32) >= tg) & ((uint32)(u3 >> 32) >= tg);
                if (__all(ok)) break;
            }
            hp[0 * HH + w * 64 + l] = __uint_as_float((uint32)u0);
            hp[1 * HH + w * 64 + l] = __uint_as_float((uint32)u1);
            hp[2 * HH + w * 64 + l] = __uint_as_float((uint32)u2);
            hp[3 * HH + w * 64 + l] = __uint_as_float((uint32)u3);
        }
        // intra-wave LDS RAW: compiler's lgkmcnt covers the hp reads below.

        // ---- partials: 4 rows x 4 cols, k-window 32; h reads are 2-addr broadcasts
        float aa0=0.f,aa1=0.f,aa2=0.f,aa3=0.f;
        float ab0=0.f,ab1=0.f,ab2=0.f,ab3=0.f;
        float ac0=0.f,ac1=0.f,ac2=0.f,ac3=0.f;
        float ad0=0.f,ad1=0.f,ad2=0.f,ad3=0.f;

#define FMA4(ACC, WV, HV) \
        ACC = fmaf(WV.x, HV.x, ACC); ACC = fmaf(WV.y, HV.y, ACC); \
        ACC = fmaf(WV.z, HV.z, ACC); ACC = fmaf(WV.w, HV.w, ACC);
#define ROW(B) { \
        const float4* hr = hp4 + (B)*128 + kg*8; \
        const float4 h0=hr[0],h1=hr[1],h2=hr[2],h3=hr[3]; \
        const float4 h4=hr[4],h5=hr[5],h6=hr[6],h7=hr[7]; \
        FMA4(aa##B, wa0,h0) FMA4(aa##B, wa1,h1) FMA4(aa##B, wa2,h2) FMA4(aa##B, wa3,h3) \
        FMA4(aa##B, wa4,h4) FMA4(aa##B, wa5,h5) FMA4(aa##B, wa6,h6) FMA4(aa##B, wa7,h7) \
        FMA4(ab##B, wb0,h0) FMA4(ab##B, wb1,h1) FMA4(ab##B, wb2,h2) FMA4(ab##B, wb3,h3) \
        FMA4(ab##B, wb4,h4) FMA4(ab##B, wb5,h5) FMA4(ab##B, wb6,h6) FMA4(ab##B, wb7,h7) \
        FMA4(ac##B, wc0,h0) FMA4(ac##B, wc1,h1) FMA4(ac##B, wc2,h2) FMA4(ac##B, wc3,h3) \
        FMA4(ac##B, wc4,h4) FMA4(ac##B, wc5,h5) FMA4(ac##B, wc6,h6) FMA4(ac##B, wc7,h7) \
        FMA4(ad##B, wd0,h0) FMA4(ad##B, wd1,h1) FMA4(ad##B, wd2,h2) FMA4(ad##B, wd3,h3) \
        FMA4(ad##B, wd4,h4) FMA4(ad##B, wd5,h5) FMA4(ad##B, wd6,h6) FMA4(ad##B, wd7,h7) }

        ROW(0) __builtin_amdgcn_sched_barrier(0);
        ROW(1) __builtin_amdgcn_sched_barrier(0);
        ROW(2) __builtin_amdgcn_sched_barrier(0);
        ROW(3) __builtin_amdgcn_sched_barrier(0);
#undef ROW
#undef FMA4

        // pack: SCALAR layout pbuf[kg*512 + row*128 + col]; per store-instr the
        // 64 lanes write 2x32 consecutive floats -> conflict-free
#define PK(B) \
        pbuf[kg*512 + (B)*128 + j     ] = aa##B; \
        pbuf[kg*512 + (B)*128 + j + 32] = ab##B; \
        pbuf[kg*512 + (B)*128 + j + 64] = ac##B; \
        pbuf[kg*512 + (B)*128 + j + 96] = ad##B;
        PK(0) PK(1) PK(2) PK(3)
#undef PK
        __syncthreads();                 // B: all partials ready

        // ---- reduce: ALL 512 threads, one output each: row=tid>>7, col=tid&127
        //      (addr identity: row*128+col == tid). 16 stride-1 scalar reads,
        //      1 tanh, ONE self-validating 8B publish. No drain, no flag.
        {
            const int row = tid >> 7;
            const int col = tid & 127;
            float s = pbuf[tid];
            #pragma unroll
            for (int kk = 1; kk < 16; ++kk) s += pbuf[kk * 512 + tid];
            const float xv = xall[t * MB + row];
            s = tanhf(s + xv * wih_s[col] + bias_s[col]);
            const ull pub = ((ull)(uint32)(t + 1) << 32) | (ull)__float_as_uint(s);
            AS(&hbufU[(size_t)(p ^ 1) * BATCH * HH
                      + (size_t)(bbase + row) * HH + jbase + col], pub);
            // own-slice shortcut for own-block consumer waves next step
            hp[row * HH + jbase + col] = s;
        }
        __syncthreads();                 // C: pbuf WAR + own-slice visible
    }
}

__global__ __launch_bounds__(256) void rnn_tail_kernel(
    const ull* __restrict__ hfinU,    // final h in buf 0 (TT even), (tag|bits)
    const float* __restrict__ lin_W, const float* __restrict__ lin_b,
    const int* __restrict__ y, float* __restrict__ out)
{
    __shared__ float redf[256];
    __shared__ int   redi[256];
    const int b = threadIdx.x;
    const ull* hrow = hfinU + (size_t)b * HH;

    float acc[NCLS];
    #pragma unroll
    for (int c = 0; c < NCLS; ++c) acc[c] = lin_b[c];
    // k-outer: h read ONCE; per-class add order identical to the original
    // (acc[c] += h0*w.x + h1*w.y + h2*w.z + h3*w.w, k ascending) -> bit-exact.
    for (int k = 0; k < HH; k += 4) {
        const float h0 = __uint_as_float((uint32)hrow[k + 0]);
        const float h1 = __uint_as_float((uint32)hrow[k + 1]);
        const float h2 = __uint_as_float((uint32)hrow[k + 2]);
        const float h3 = __uint_as_float((uint32)hrow[k + 3]);
        #pragma unroll
        for (int c = 0; c < NCLS; ++c) {
            const float4 wv = *(const float4*)(lin_W + (size_t)c * HH + k);
            acc[c] += h0 * wv.x + h1 * wv.y + h2 * wv.z + h3 * wv.w;
        }
    }
    int am = 0; float m = acc[0];
    #pragma unroll
    for (int c = 1; c < NCLS; ++c) if (acc[c] > m) { m = acc[c]; am = c; } // first-max
    float sum = 0.0f;
    #pragma unroll
    for (int c = 0; c < NCLS; ++c) sum += expf(acc[c] - m);
    const float lse = m + logf(sum);
    const int yy = y[b];
    redf[b] = lse - acc[yy];
    redi[b] = (am == yy) ? 1 : 0;
    __syncthreads();
    for (int s2 = 128; s2 > 0; s2 >>= 1) {
        if (b < s2) { redf[b] += redf[b + s2]; redi[b] += redi[b + s2]; }
        __syncthreads();
    }
    if (b == 0) {
        out[0] = redf[0] / (float)BATCH;  // loss
        out[1] = (float)redi[0];          // correct count
    }
}

extern "C" void kernel_launch(void* const* d_in, const int* in_sizes, int n_in,
                              void* d_out, int out_size, void* d_ws, size_t ws_size,
                              hipStream_t stream) {
    const float* inputs = (const float*)d_in[0];
    const int*   y      = (const int*)  d_in[1];
    const int*   order  = (const int*)  d_in[2];
    const float* W_ih   = (const float*)d_in[3];
    const float* b_ih   = (const float*)d_in[4];
    const float* W_hh   = (const float*)d_in[5];
    const float* b_hh   = (const float*)d_in[6];
    const float* lin_W  = (const float*)d_in[7];
    const float* lin_b  = (const float*)d_in[8];
    float* out = (float*)d_out;

    ull* hbufU = (ull*)((char*)d_ws + 8192);

    // zero tags (and values) — REQUIRED for bench re-runs (stale tags >= t
    // would admit stale h). 2 MB, ~1 us.
    hipMemsetAsync(hbufU, 0, (size_t)2 * BATCH * HH * sizeof(ull), stream);

    void* args[] = {(void*)&inputs, (void*)&order, (void*)&W_ih, (void*)&b_ih,
                    (void*)&W_hh, (void*)&b_hh, (void*)&hbufU};
    hipError_t err = hipLaunchCooperativeKernel((void*)rnn_main_kernel,
                                                dim3(NB * NJ), dim3(NT), args, 0, stream);
    if (err != hipSuccess) {
        hipLaunchKernelGGL(rnn_main_kernel, dim3(NB * NJ), dim3(NT), 0, stream,
                           inputs, order, W_ih, b_ih, W_hh, b_hh, hbufU);
    }

    hipLaunchKernelGGL(rnn_tail_kernel, dim3(1), dim3(256), 0, stream,
                       hbufU, lin_W, lin_b, y, out);
}

// Round 17
// 2022.236 us; speedup vs baseline: 1.0337x; 1.0337x over previous
//
#include <hip/hip_runtime.h>
#include <math.h>

#define BATCH 256
#define TT    784
#define HH    512
#define NCLS  10

#define NB 64          // batch groups
#define NJ 4           // blocks per group; block owns 128 cols
#define MB 4           // batch rows per group
#define HJ 128         // output cols per block
#define NT 512         // threads per block (8 waves, 2/SIMD)

typedef unsigned long long ull;
typedef unsigned int uint32;

#define AL(p)    __hip_atomic_load((p), __ATOMIC_RELAXED, __HIP_MEMORY_SCOPE_AGENT)
#define AS(p, v) __hip_atomic_store((p), (v), __ATOMIC_RELAXED, __HIP_MEMORY_SCOPE_AGENT)

// FINAL STATE (R0-R16) — R12 backbone, best measured 2023-2027 us (3 runs).
// Session: 3214 -> 2023 us (-37%). Key structure:
//  * Self-validating (value,tag) 8B publishes (R12, -26%): producer stores
//    (tag<<32)|float_bits as ONE relaxed 8B atomic — no vmcnt drain, no
//    flag; consumer polls its OWN words, tag-match => value in-register.
//    Killed 2 of 3 serial L2 round-trips per step.
//  * All-thread scalar reduce, conflict-free scalar pbuf (R8, -12%).
//  * Own-slice stays on-CU via LDS + barrier C (R7/R13: L2 route = loss).
//  * Refuted by experiment: poll pre-issue (R14, races publish), L2-local
//    sc0 poll (R16, sc1 invalidates the line -> L3 miss anyway), barrier-C
//    removal (R13), 2 blocks/CU or 4 waves/SIMD (R6/R9), weight-residency
//    attributes (R1-R7: unified VGPR+AGPR file already holds them).
//  * Cross-CU reads MUST bypass L1 (R10: absmax=8 from stale L1 via
//    plain-cached global_load_lds; aux=0x11 fixes DMA, AL/AS fix loads).
//  * VALUBusy on gfx950 is ~2x inflated (gfx94x SIMD-16 formula): 80 ~= 36%.
//  * Converged budget ~6190 cyc/step: 2048 FMA issue floor (no fp32 MFMA)
//    + ~900 stage/pack/reduce + ~500 publish->detect (irreducible data dep)
//    + ~700 barriers/skew + overlap losses. Latency-bound, not pipe-bound.
//
// d_ws layout:
//   [8192, 8192+2MB) : hbufU ull[2][BATCH][HH] — (tag<<32)|float_bits,
//                      agent-relaxed. Tags zeroed by hipMemsetAsync each
//                      launch (resets between bench iterations).

// Opaque register pin: weights become outputs of a volatile asm — cannot be
// rematerialized or sunk into the loop.
#define PIN(V) asm volatile("" : "+v"((V).x), "+v"((V).y), "+v"((V).z), "+v"((V).w))

__global__ __launch_bounds__(NT)
__attribute__((amdgpu_waves_per_eu(2, 2)))
void rnn_main_kernel(
    const float* __restrict__ inputs, const int* __restrict__ order,
    const float* __restrict__ W_ih, const float* __restrict__ b_ih,
    const float* __restrict__ W_hh, const float* __restrict__ b_hh,
    ull* __restrict__ hbufU)
{
    __shared__ float hp[MB * HH];            // 8 KB : h tile (canonical col layout)
    __shared__ float pbuf[16 * MB * HJ];     // 32 KB: partials, SCALAR [kk][row][col]
    __shared__ float xall[TT * MB];          // 12.25 KB: inputs[b][order[t]]
    __shared__ float wih_s[HJ];
    __shared__ float bias_s[HJ];

    const int tid   = threadIdx.x;
    const int blk   = blockIdx.x;
    const int bb    = blk & (NB - 1);        // group; members blk=bb+64g -> same XCD under %8
    const int jjg   = blk >> 6;              // producer id 0..3: cols [jjg*128, +128)
    const int jbase = jjg * HJ;
    const int bbase = bb * MB;
    const int j   = tid & 31;                // base col lane: cols {j, j+32, j+64, j+96}
    const int kg  = tid >> 5;                // k-chunk 0..15 (32 k each)
    const int w   = tid >> 6;                // wave: k-window [64w,+64), producer g=w>>1
    const int g   = w >> 1;
    const int l   = tid & 63;

    // ---- W_hh slice in NAMED registers: 4 cols x 32 k = 32 float4
    //      (live in the unified VGPR/AGPR file; VALU reads them directly)
    const float4* wpa = (const float4*)(W_hh + (size_t)(jbase + j +  0) * HH + kg * 32);
    const float4* wpb = (const float4*)(W_hh + (size_t)(jbase + j + 32) * HH + kg * 32);
    const float4* wpc = (const float4*)(W_hh + (size_t)(jbase + j + 64) * HH + kg * 32);
    const float4* wpd = (const float4*)(W_hh + (size_t)(jbase + j + 96) * HH + kg * 32);
    float4 wa0 = wpa[0], wa1 = wpa[1], wa2 = wpa[2], wa3 = wpa[3];
    float4 wa4 = wpa[4], wa5 = wpa[5], wa6 = wpa[6], wa7 = wpa[7];
    float4 wb0 = wpb[0], wb1 = wpb[1], wb2 = wpb[2], wb3 = wpb[3];
    float4 wb4 = wpb[4], wb5 = wpb[5], wb6 = wpb[6], wb7 = wpb[7];
    float4 wc0 = wpc[0], wc1 = wpc[1], wc2 = wpc[2], wc3 = wpc[3];
    float4 wc4 = wpc[4], wc5 = wpc[5], wc6 = wpc[6], wc7 = wpc[7];
    float4 wd0 = wpd[0], wd1 = wpd[1], wd2 = wpd[2], wd3 = wpd[3];
    float4 wd4 = wpd[4], wd5 = wpd[5], wd6 = wpd[6], wd7 = wpd[7];

    PIN(wa0); PIN(wa1); PIN(wa2); PIN(wa3);
    PIN(wa4); PIN(wa5); PIN(wa6); PIN(wa7);
    PIN(wb0); PIN(wb1); PIN(wb2); PIN(wb3);
    PIN(wb4); PIN(wb5); PIN(wb6); PIN(wb7);
    PIN(wc0); PIN(wc1); PIN(wc2); PIN(wc3);
    PIN(wc4); PIN(wc5); PIN(wc6); PIN(wc7);
    PIN(wd0); PIN(wd1); PIN(wd2); PIN(wd3);
    PIN(wd4); PIN(wd5); PIN(wd6); PIN(wd7);

    if (tid < HJ) {
        wih_s[tid]  = W_ih[jbase + tid];
        bias_s[tid] = b_ih[jbase + tid] + b_hh[jbase + tid];
    }
    for (int idx = tid; idx < TT * MB; idx += NT) {
        const int t = idx >> 2;
        const int b = idx & (MB - 1);
        xall[idx] = inputs[(size_t)(bbase + b) * TT + order[t]];
    }
    ((float4*)hp)[tid] = make_float4(0.f, 0.f, 0.f, 0.f);   // h_0 = 0 (8 KB)
    __syncthreads();

    const float4* hp4 = (const float4*)hp;

    for (int t = 0; t < TT; ++t) {
        const int p = t & 1;

        // ---- per-wave gate+stage fused: each lane polls ITS OWN 4 pair-words
        //      (one per batch row at col w*64+l). Tag match => value already
        //      in-register; 4 ds_writes finish the stage. No flag, no fetch.
        if (t > 0 && g != jjg) {
            const uint32 tg = (uint32)t;
            const ull* src = hbufU + (size_t)p * BATCH * HH
                             + (size_t)bbase * HH + w * 64 + l;
            ull u0, u1, u2, u3;
            for (;;) {
                u0 = AL(src);            u1 = AL(src + HH);
                u2 = AL(src + 2 * HH);   u3 = AL(src + 3 * HH);
                const int ok = ((uint32)(u0 >> 32) >= tg) & ((uint32)(u1 >> 32) >= tg)
                             & ((uint32)(u2 >> 32) >= tg) & ((uint32)(u3 >> 32) >= tg);
                if (__all(ok)) break;
            }
            hp[0 * HH + w * 64 + l] = __uint_as_float((uint32)u0);
            hp[1 * HH + w * 64 + l] = __uint_as_float((uint32)u1);
            hp[2 * HH + w * 64 + l] = __uint_as_float((uint32)u2);
            hp[3 * HH + w * 64 + l] = __uint_as_float((uint32)u3);
        }
        // intra-wave LDS RAW: compiler's lgkmcnt covers the hp reads below.

        // ---- partials: 4 rows x 4 cols, k-window 32; h reads are 2-addr broadcasts
        float aa0=0.f,aa1=0.f,aa2=0.f,aa3=0.f;
        float ab0=0.f,ab1=0.f,ab2=0.f,ab3=0.f;
        float ac0=0.f,ac1=0.f,ac2=0.f,ac3=0.f;
        float ad0=0.f,ad1=0.f,ad2=0.f,ad3=0.f;

#define FMA4(ACC, WV, HV) \
        ACC = fmaf(WV.x, HV.x, ACC); ACC = fmaf(WV.y, HV.y, ACC); \
        ACC = fmaf(WV.z, HV.z, ACC); ACC = fmaf(WV.w, HV.w, ACC);
#define ROW(B) { \
        const float4* hr = hp4 + (B)*128 + kg*8; \
        const float4 h0=hr[0],h1=hr[1],h2=hr[2],h3=hr[3]; \
        const float4 h4=hr[4],h5=hr[5],h6=hr[6],h7=hr[7]; \
        FMA4(aa##B, wa0,h0) FMA4(aa##B, wa1,h1) FMA4(aa##B, wa2,h2) FMA4(aa##B, wa3,h3) \
        FMA4(aa##B, wa4,h4) FMA4(aa##B, wa5,h5) FMA4(aa##B, wa6,h6) FMA4(aa##B, wa7,h7) \
        FMA4(ab##B, wb0,h0) FMA4(ab##B, wb1,h1) FMA4(ab##B, wb2,h2) FMA4(ab##B, wb3,h3) \
        FMA4(ab##B, wb4,h4) FMA4(ab##B, wb5,h5) FMA4(ab##B, wb6,h6) FMA4(ab##B, wb7,h7) \
        FMA4(ac##B, wc0,h0) FMA4(ac##B, wc1,h1) FMA4(ac##B, wc2,h2) FMA4(ac##B, wc3,h3) \
        FMA4(ac##B, wc4,h4) FMA4(ac##B, wc5,h5) FMA4(ac##B, wc6,h6) FMA4(ac##B, wc7,h7) \
        FMA4(ad##B, wd0,h0) FMA4(ad##B, wd1,h1) FMA4(ad##B, wd2,h2) FMA4(ad##B, wd3,h3) \
        FMA4(ad##B, wd4,h4) FMA4(ad##B, wd5,h5) FMA4(ad##B, wd6,h6) FMA4(ad##B, wd7,h7) }

        ROW(0) __builtin_amdgcn_sched_barrier(0);
        ROW(1) __builtin_amdgcn_sched_barrier(0);
        ROW(2) __builtin_amdgcn_sched_barrier(0);
        ROW(3) __builtin_amdgcn_sched_barrier(0);
#undef ROW
#undef FMA4

        // pack: SCALAR layout pbuf[kg*512 + row*128 + col]; per store-instr the
        // 64 lanes write 2x32 consecutive floats -> conflict-free
#define PK(B) \
        pbuf[kg*512 + (B)*128 + j     ] = aa##B; \
        pbuf[kg*512 + (B)*128 + j + 32] = ab##B; \
        pbuf[kg*512 + (B)*128 + j + 64] = ac##B; \
        pbuf[kg*512 + (B)*128 + j + 96] = ad##B;
        PK(0) PK(1) PK(2) PK(3)
#undef PK
        __syncthreads();                 // B: all partials ready

        // ---- reduce: ALL 512 threads, one output each: row=tid>>7, col=tid&127
        //      (addr identity: row*128+col == tid). 16 stride-1 scalar reads,
        //      1 tanh, ONE self-validating 8B publish. No drain, no flag.
        {
            const int row = tid >> 7;
            const int col = tid & 127;
            float s = pbuf[tid];
            #pragma unroll
            for (int kk = 1; kk < 16; ++kk) s += pbuf[kk * 512 + tid];
            const float xv = xall[t * MB + row];
            s = tanhf(s + xv * wih_s[col] + bias_s[col]);
            const ull pub = ((ull)(uint32)(t + 1) << 32) | (ull)__float_as_uint(s);
            AS(&hbufU[(size_t)(p ^ 1) * BATCH * HH
                      + (size_t)(bbase + row) * HH + jbase + col], pub);
            // own-slice shortcut for own-block consumer waves next step
            hp[row * HH + jbase + col] = s;
        }
        __syncthreads();                 // C: pbuf WAR + own-slice visible
    }
}

__global__ __launch_bounds__(256) void rnn_tail_kernel(
    const ull* __restrict__ hfinU,    // final h in buf 0 (TT even), (tag|bits)
    const float* __restrict__ lin_W, const float* __restrict__ lin_b,
    const int* __restrict__ y, float* __restrict__ out)
{
    __shared__ float redf[256];
    __shared__ int   redi[256];
    const int b = threadIdx.x;
    const ull* hrow = hfinU + (size_t)b * HH;

    float acc[NCLS];
    #pragma unroll
    for (int c = 0; c < NCLS; ++c) acc[c] = lin_b[c];
    // k-outer: h read ONCE; per-class add order identical to the original
    // (acc[c] += h0*w.x + h1*w.y + h2*w.z + h3*w.w, k ascending) -> bit-exact.
    for (int k = 0; k < HH; k += 4) {
        const float h0 = __uint_as_float((uint32)hrow[k + 0]);
        const float h1 = __uint_as_float((uint32)hrow[k + 1]);
        const float h2 = __uint_as_float((uint32)hrow[k + 2]);
        const float h3 = __uint_as_float((uint32)hrow[k + 3]);
        #pragma unroll
        for (int c = 0; c < NCLS; ++c) {
            const float4 wv = *(const float4*)(lin_W + (size_t)c * HH + k);
            acc[c] += h0 * wv.x + h1 * wv.y + h2 * wv.z + h3 * wv.w;
        }
    }
    int am = 0; float m = acc[0];
    #pragma unroll
    for (int c = 1; c < NCLS; ++c) if (acc[c] > m) { m = acc[c]; am = c; } // first-max
    float sum = 0.0f;
    #pragma unroll
    for (int c = 0; c < NCLS; ++c) sum += expf(acc[c] - m);
    const float lse = m + logf(sum);
    const int yy = y[b];
    redf[b] = lse - acc[yy];
    redi[b] = (am == yy) ? 1 : 0;
    __syncthreads();
    for (int s2 = 128; s2 > 0; s2 >>= 1) {
        if (b < s2) { redf[b] += redf[b + s2]; redi[b] += redi[b + s2]; }
        __syncthreads();
    }
    if (b == 0) {
        out[0] = redf[0] / (float)BATCH;  // loss
        out[1] = (float)redi[0];          // correct count
    }
}

extern "C" void kernel_launch(void* const* d_in, const int* in_sizes, int n_in,
                              void* d_out, int out_size, void* d_ws, size_t ws_size,
                              hipStream_t stream) {
    const float* inputs = (const float*)d_in[0];
    const int*   y      = (const int*)  d_in[1];
    const int*   order  = (const int*)  d_in[2];
    const float* W_ih   = (const float*)d_in[3];
    const float* b_ih   = (const float*)d_in[4];
    const float* W_hh   = (const float*)d_in[5];
    const float* b_hh   = (const float*)d_in[6];
    const float* lin_W  = (const float*)d_in[7];
    const float* lin_b  = (const float*)d_in[8];
    float* out = (float*)d_out;

    ull* hbufU = (ull*)((char*)d_ws + 8192);

    // zero tags (and values) — REQUIRED for bench re-runs (stale tags >= t
    // would admit stale h). 2 MB, ~1 us.
    hipMemsetAsync(hbufU, 0, (size_t)2 * BATCH * HH * sizeof(ull), stream);

    void* args[] = {(void*)&inputs, (void*)&order, (void*)&W_ih, (void*)&b_ih,
                    (void*)&W_hh, (void*)&b_hh, (void*)&hbufU};
    hipError_t err = hipLaunchCooperativeKernel((void*)rnn_main_kernel,
                                                dim3(NB * NJ), dim3(NT), args, 0, stream);
    if (err != hipSuccess) {
        hipLaunchKernelGGL(rnn_main_kernel, dim3(NB * NJ), dim3(NT), 0, stream,
                           inputs, order, W_ih, b_ih, W_hh, b_hh, hbufU);
    }

    hipLaunchKernelGGL(rnn_tail_kernel, dim3(1), dim3(256), 0, stream,
                       hbufU, lin_W, lin_b, y, out);
}